// Round 28
// baseline (200.940 us; speedup 1.0000x reference)
//
#include <hip/hip_runtime.h>
#include <math.h>

#define B_ 2
#define M_ 32768
#define N_ 4096
#define D_ 128
#define K_ 8
#define G_ 16
#define NC_ 4096
#define CW_ 0.0625f
#define CAP_ 224

typedef _Float16 half4_t __attribute__((ext_vector_type(4)));
typedef float f32x4 __attribute__((ext_vector_type(4)));
typedef unsigned long long u64;

// ---------------- frozen selection semantics (verified R15) ----------------
//   sp2 = (z*z + y*y) + x*x            descending plain, no FMA
//   sg2 = (gz*gz + gy*gy) + gx*gx      descending plain, no FMA
//   dot = fma(gz,pz, fma(gy,py, gx*px))  ascending FMA chain
//   d2  = fma(dot,-2, sg2+sp2)          == (sg2+sp2) - 2*dot bitwise
//   dist= sqrtf(fmaxf(d2,0)); order by (dist, index) lexicographic.
// u64 key = (dist_bits<<32)|idx: dist>=0 so u64 order == lex(dist,idx).
// ---------------------------------------------------------------------------
__device__ __forceinline__ void lex64_insert(u64 k, u64* kd)
{
    if (k < kd[7]) {
        kd[7] = k;
#pragma unroll
        for (int u = 6; u >= 0; --u) {
            if (kd[u+1] < kd[u]) { u64 t = kd[u]; kd[u] = kd[u+1]; kd[u+1] = t; }
        }
    }
}

__device__ __forceinline__ u64 mk_key(float dist, int idx)
{
    return ((u64)__float_as_uint(dist) << 32) | (unsigned)idx;
}

__device__ __forceinline__ void fold64(u64* kd, int mask)
{
    u64 ok[8];
#pragma unroll
    for (int u = 0; u < 8; ++u) ok[u] = __shfl_xor((long long)kd[u], mask);
#pragma unroll
    for (int u = 0; u < 8; ++u) lex64_insert(ok[u], kd);
}

// ---------------------------- prep kernels (fused) -------------------------
__global__ __launch_bounds__(256) void prep_hist_all(
    const float* __restrict__ pts, const float* __restrict__ grid_c,
    int* __restrict__ hist)
{
    const int i = blockIdx.x * 256 + threadIdx.x;
    const int NP = B_ * N_;
    if (i < NP) {
        const float x = pts[i*3+0], y = pts[i*3+1], z = pts[i*3+2];
        const int cx = min(G_-1, (int)(x * 16.0f));
        const int cy = min(G_-1, (int)(y * 16.0f));
        const int cz = min(G_-1, (int)(z * 16.0f));
        atomicAdd(&hist[(i >> 12) * NC_ + cz*256 + cy*16 + cx], 1);
    } else if (i < NP + B_ * M_) {
        const int j = i - NP;
        const float x = grid_c[j*3+0], y = grid_c[j*3+1], z = grid_c[j*3+2];
        const int cx = min(G_-1, (int)(x * 16.0f));
        const int cy = min(G_-1, (int)(y * 16.0f));
        const int cz = min(G_-1, (int)(z * 16.0f));
        atomicAdd(&hist[(B_ + (j >> 15)) * NC_ + cz*256 + cy*16 + cx], 1);
    }
}

__global__ __launch_bounds__(256) void prep_scan(
    const int* __restrict__ hist, int* __restrict__ cstart, int* __restrict__ ccur)
{
    __shared__ int wsum[4];
    const int b = blockIdx.x, t = threadIdx.x;
    const int lane = t & 63, wv = t >> 6;
    int v[16]; int s = 0;
#pragma unroll
    for (int j = 0; j < 16; ++j) { v[j] = hist[b*NC_ + t*16 + j]; s += v[j]; }
    int inc = s;
#pragma unroll
    for (int o = 1; o < 64; o <<= 1) {
        int x = __shfl_up(inc, o);
        if (lane >= o) inc += x;
    }
    if (lane == 63) wsum[wv] = inc;
    __syncthreads();
    int woff = 0;
    for (int w2 = 0; w2 < wv; ++w2) woff += wsum[w2];
    int excl = woff + inc - s;
#pragma unroll
    for (int j = 0; j < 16; ++j) {
        cstart[b*(NC_+1) + t*16 + j] = excl;
        ccur[b*NC_ + t*16 + j] = excl;
        excl += v[j];
    }
    if (t == 255) cstart[b*(NC_+1) + NC_] = excl;
}

__global__ __launch_bounds__(256) void prep_scatter_all(
    const float* __restrict__ pts, const float* __restrict__ grid_c,
    const float* __restrict__ W2, int* __restrict__ ccur,
    float4* __restrict__ p4s, int* __restrict__ sidx,
    float4* __restrict__ q4s, int* __restrict__ qmap,
    _Float16* __restrict__ w2t_hi)
{
#pragma clang fp contract(off)
    const int i = blockIdx.x * 256 + threadIdx.x;
    const int NP = B_ * N_, NQ = B_ * M_;
    if (i < NP) {
        const int b = i >> 12, loc = i & (N_-1);
        const float x = pts[i*3+0], y = pts[i*3+1], z = pts[i*3+2];
        const int cx = min(G_-1, (int)(x * 16.0f));
        const int cy = min(G_-1, (int)(y * 16.0f));
        const int cz = min(G_-1, (int)(z * 16.0f));
        const int pos = atomicAdd(&ccur[b*NC_ + cz*256 + cy*16 + cx], 1);
        float4 v; v.x = x; v.y = y; v.z = z;
        v.w = (z * z + y * y) + x * x;          // FROZEN descending plain
        p4s[b*N_ + pos] = v;
        sidx[b*N_ + pos] = loc;
    } else if (i < NP + NQ) {
        const int j = i - NP;
        const int b = j >> 15;
        const float x = grid_c[j*3+0], y = grid_c[j*3+1], z = grid_c[j*3+2];
        const int cx = min(G_-1, (int)(x * 16.0f));
        const int cy = min(G_-1, (int)(y * 16.0f));
        const int cz = min(G_-1, (int)(z * 16.0f));
        const int pos = atomicAdd(&ccur[(B_ + b)*NC_ + cz*256 + cy*16 + cx], 1);
        float4 v; v.x = x; v.y = y; v.z = z;
        v.w = (z * z + y * y) + x * x;          // FROZEN descending plain
        q4s[(size_t)b*M_ + pos] = v;
        qmap[(size_t)b*M_ + pos] = j;
    } else if (i < NP + NQ + D_ * D_) {
        const int m = i - NP - NQ;
        const int n = m >> 7, k = m & 127;
        w2t_hi[m] = (_Float16)W2[k * D_ + n];
    }
}

// ------------------------------- knn (selection logic byte-identical) ------
// Staging now uses 2 lanes per row (shfl'd row descriptors) -> half the
// serial dependent-load chain. Scan/fold/ring/weights unchanged.
__global__ __launch_bounds__(256) void knn_kernel(
    const float4* __restrict__ q4s, const int* __restrict__ qmap,
    const float4* __restrict__ p4s, const int* __restrict__ sidx,
    const int* __restrict__ cstart, const int* __restrict__ qstart,
    int* __restrict__ out_idx, float* __restrict__ out_w)
{
#pragma clang fp contract(off)
    __shared__ float4 spt[4][CAP_];
    __shared__ int    sil[4][CAP_];
    __shared__ int    rtab[4][32][2];

    const int tid  = threadIdx.x;
    const int wv   = tid >> 6;
    const int lane = tid & 63;
    const int gci  = blockIdx.x * 4 + wv;
    const int b    = gci >> 12;
    const int cid  = gci & (NC_ - 1);
    const int cx = cid & 15, cy = (cid >> 4) & 15, cz = cid >> 8;

    const int* __restrict__ cs = cstart + b * (NC_ + 1);
    const int qs0 = qstart[b * (NC_ + 1) + cid];
    const int nq  = qstart[b * (NC_ + 1) + cid + 1] - qs0;

    const float4* p4 = p4s + (size_t)b * N_;
    const int*    sx = sidx + (size_t)b * N_;

    const int z0 = max(0, cz-2), z1 = min(G_-1, cz+2);
    const int y0 = max(0, cy-2), y1 = min(G_-1, cy+2);
    const int x0 = max(0, cx-2), x1 = min(G_-1, cx+2);
    const int ny = y1 - y0 + 1;
    const int nrows = (z1 - z0 + 1) * ny;

    int myS = 0, myLen = 0;
    if (nq > 0 && lane < nrows) {
        const int zz = z0 + lane / ny;
        const int yy = y0 + lane % ny;
        const int cb = zz*256 + yy*16;
        myS   = cs[cb + x0];
        myLen = cs[cb + x1 + 1] - myS;
    }
    int inc = myLen;
#pragma unroll
    for (int o = 1; o < 64; o <<= 1) {
        int v = __shfl_up(inc, o);
        if (lane >= o) inc += v;
    }
    const int off = inc - myLen;
    const int tot = __shfl(inc, 63);
    const bool ovf = (tot > CAP_);
    if (nq > 0 && lane < nrows) {
        rtab[wv][lane][0] = myS;
        rtab[wv][lane][1] = myLen;
    }
    if (nq > 0 && !ovf) {
        // 2 lanes per row: row = lane>>1, half = lane&1
        const int row = lane >> 1;
        const int S2 = __shfl(myS, row);
        const int L2 = __shfl(myLen, row);
        const int O2 = __shfl(off, row);
        for (int t = (lane & 1); t < L2; t += 2) {
            spt[wv][O2 + t] = p4[S2 + t];
            sil[wv][O2 + t] = sx[S2 + t];
        }
    }
    __syncthreads();

    const int qg  = lane >> 2;
    const int sub = lane & 3;

    for (int q0 = 0; q0 < nq; q0 += 16) {
        const bool act = (q0 + qg) < nq;
        float gx = 0.f, gy = 0.f, gz = 0.f, sg2 = 0.f;
        int qorig = 0;
        if (act) {
            const size_t slot = (size_t)b * M_ + qs0 + q0 + qg;
            const float4 qv = q4s[slot];
            gx = qv.x; gy = qv.y; gz = qv.z; sg2 = qv.w;   // FROZEN sg2
            qorig = qmap[slot];
        }

        u64 kd[8];
#pragma unroll
        for (int u = 0; u < 8; ++u) kd[u] = ~0ull;

        if (act) {
            if (!ovf) {
                const int ts = (sub * tot) >> 2;
                const int te = ((sub + 1) * tot) >> 2;
                for (int t = ts; t < te; ++t) {
                    const float4 pp = spt[wv][t];
                    const float dot  = fmaf(gz, pp.z, fmaf(gy, pp.y, gx * pp.x));
                    const float d2   = fmaf(dot, -2.0f, sg2 + pp.w);
                    const float dist = sqrtf(fmaxf(d2, 0.0f));
                    lex64_insert(mk_key(dist, sil[wv][t]), kd);
                }
            } else {
                const int r0 = (sub * nrows) >> 2;
                const int r1 = ((sub + 1) * nrows) >> 2;
                for (int r = r0; r < r1; ++r) {
                    const int gs = rtab[wv][r][0];
                    const int ln = rtab[wv][r][1];
                    for (int t = 0; t < ln; ++t) {
                        const float4 pp = p4[gs + t];
                        const float dot  = fmaf(gz, pp.z, fmaf(gy, pp.y, gx * pp.x));
                        const float d2   = fmaf(dot, -2.0f, sg2 + pp.w);
                        const float dist = sqrtf(fmaxf(d2, 0.0f));
                        lex64_insert(mk_key(dist, sx[gs + t]), kd);
                    }
                }
            }
        }
        fold64(kd, 1);
        fold64(kd, 2);

        int R = 2;
        while (R < G_ - 1) {
            const float bd7 = __uint_as_float((unsigned)(kd[7] >> 32));
            const bool need = act && !(bd7 < (float)R * CW_ - 1e-5f);
            if (!__any(need)) break;
            ++R;
            if (need) {
                u64 fk[8];
#pragma unroll
                for (int u = 0; u < 8; ++u) fk[u] = ~0ull;
                int m2 = 0;
                for (int zz = cz - R; zz <= cz + R; ++zz) {
                    if (zz < 0 || zz > G_-1) continue;
                    for (int yy = cy - R; yy <= cy + R; ++yy) {
                        if (yy < 0 || yy > G_-1) continue;
                        const int ch = max(abs(zz - cz), abs(yy - cy));
                        if (((m2++) & 3) != sub) continue;
                        const int cb = zz*256 + yy*16;
                        int s0, e0, s1 = 0, e1 = 0;
                        if (ch == R) {
                            s0 = cs[cb + max(0, cx-R)];
                            e0 = cs[cb + min(G_-1, cx+R) + 1];
                        } else {
                            const int xl = cx - R, xr = cx + R;
                            s0 = (xl >= 0)    ? cs[cb+xl]   : 0;
                            e0 = (xl >= 0)    ? cs[cb+xl+1] : 0;
                            s1 = (xr <= G_-1) ? cs[cb+xr]   : 0;
                            e1 = (xr <= G_-1) ? cs[cb+xr+1] : 0;
                        }
                        for (int t = s0; t < e0; ++t) {
                            const float4 pp = p4[t];
                            const float dot  = fmaf(gz, pp.z, fmaf(gy, pp.y, gx * pp.x));
                            const float d2   = fmaf(dot, -2.0f, sg2 + pp.w);
                            const float dist = sqrtf(fmaxf(d2, 0.0f));
                            lex64_insert(mk_key(dist, sx[t]), fk);
                        }
                        for (int t = s1; t < e1; ++t) {
                            const float4 pp = p4[t];
                            const float dot  = fmaf(gz, pp.z, fmaf(gy, pp.y, gx * pp.x));
                            const float d2   = fmaf(dot, -2.0f, sg2 + pp.w);
                            const float dist = sqrtf(fmaxf(d2, 0.0f));
                            lex64_insert(mk_key(dist, sx[t]), fk);
                        }
                    }
                }
                fold64(fk, 1);
                fold64(fk, 2);
#pragma unroll
                for (int u = 0; u < 8; ++u) lex64_insert(fk[u], kd);
            }
        }

        if (act && sub == 0) {
            float wk8[8];
#pragma unroll
            for (int u = 0; u < 8; ++u) {
                const float dist = __uint_as_float((unsigned)(kd[u] >> 32));
                wk8[u] = 1.0f / (dist + 1e-6f);
            }
            float wsum = wk8[0];
#pragma unroll
            for (int u = 1; u < 8; ++u) wsum = wsum + wk8[u];
            const float winv = 1.0f / wsum;
#pragma unroll
            for (int u = 0; u < 8; ++u) {
                out_idx[qorig * 8 + u] = (int)(kd[u] & 0xffffffffu);
                out_w[qorig * 8 + u]   = wk8[u] * winv;
            }
        }
    }
}

// ------------- gno: 512 threads / 16 queries per block ---------------------
// Halves block count (per-block fixed costs: gather, barriers, B reloads)
// while keeping 32 waves/CU (4 blocks x 8 waves; LDS 36.9KB). Math bit-
// identical to R27 (same products, same order; M-dim tiled 2x).
#define HSTR 132
__global__ __launch_bounds__(512) void gno_kernel(
    const float* __restrict__ grid_c, const float* __restrict__ pts,
    const float* __restrict__ feats,
    const float* __restrict__ W1, const float* __restrict__ b1,
    const _Float16* __restrict__ w2t_hi,
    const float* __restrict__ b2,
    const float* __restrict__ gmm, const float* __restrict__ bta,
    const int* __restrict__ kidx, const float* __restrict__ kw,
    float* __restrict__ out)
{
    __shared__ __align__(16) _Float16 smem_h[128][HSTR];     // 33792 B
    _Float16 (*kappa)[HSTR] = (_Float16(*)[HSTR])&smem_h[0][0]; // alias
    __shared__ float srel[16][8][4];
    __shared__ float swt[16][8];
    __shared__ int   sid[16][8];

    const int tid  = threadIdx.x;
    const int qb16 = blockIdx.x * 16;

    if (tid < 128) {
        const int qq = tid >> 3, k = tid & 7;
        const int gq = qb16 + qq;
        const int id = kidx[gq * 8 + k];
        sid[qq][k] = id;
        swt[qq][k] = kw[gq * 8 + k];
        const int bb = gq >> 15;
        const float* pp = pts + ((size_t)bb * N_ + id) * 3;
        srel[qq][k][0] = grid_c[gq * 3 + 0] - pp[0];
        srel[qq][k][1] = grid_c[gq * 3 + 1] - pp[1];
        srel[qq][k][2] = grid_c[gq * 3 + 2] - pp[2];
    }

    const int qs = tid >> 5;          // 0..15
    const int dg = tid & 31;

    const float4 w1r0 = *(const float4*)(W1 + dg * 4);
    const float4 w1r1 = *(const float4*)(W1 + D_ + dg * 4);
    const float4 w1r2 = *(const float4*)(W1 + 2 * D_ + dg * 4);
    const float4 w1bb = *(const float4*)(b1 + dg * 4);
    __syncthreads();

    // ---- Phase A: h via packed-f16 GELU -> LDS --------------------------
#pragma unroll
    for (int k = 0; k < 8; ++k) {
        const float rx = srel[qs][k][0];
        const float ry = srel[qs][k][1];
        const float rz = srel[qs][k][2];
        const float u0 = rx * w1r0.x + ry * w1r1.x + rz * w1r2.x + w1bb.x;
        const float u1 = rx * w1r0.y + ry * w1r1.y + rz * w1r2.y + w1bb.y;
        const float u2 = rx * w1r0.z + ry * w1r1.z + rz * w1r2.z + w1bb.z;
        const float u3 = rx * w1r0.w + ry * w1r1.w + rz * w1r2.w + w1bb.w;
        half4_t uh;
        uh[0] = (_Float16)u0; uh[1] = (_Float16)u1;
        uh[2] = (_Float16)u2; uh[3] = (_Float16)u3;
        const half4_t t  = uh * (_Float16)0.70710678118654752f;
        const half4_t t2 = t * t;
        half4_t p = t2 * (_Float16)0.1f + (_Float16)(-1.0f/3.0f);
        p = t2 * p + (_Float16)1.0f;
        const half4_t er = (t * p) * (_Float16)1.1283791670955126f;
        half4_t hv = (uh * (_Float16)0.5f) * (er + (_Float16)1.0f);
        const float am = fmaxf(fmaxf(fabsf(u0), fabsf(u1)),
                               fmaxf(fabsf(u2), fabsf(u3)));
        if (am > 0.5f) {    // exact f32 path (never fires; execz-skipped)
            hv[0] = (_Float16)(0.5f*u0*(1.0f+erff(u0*0.70710678118654752f)));
            hv[1] = (_Float16)(0.5f*u1*(1.0f+erff(u1*0.70710678118654752f)));
            hv[2] = (_Float16)(0.5f*u2*(1.0f+erff(u2*0.70710678118654752f)));
            hv[3] = (_Float16)(0.5f*u3*(1.0f+erff(u3*0.70710678118654752f)));
        }
        *(half4_t*)&smem_h[qs * 8 + k][dg * 4] = hv;
    }
    __syncthreads();

    // ---- MFMA: kappa = h @ W2; wave (mh=wv>>2, nw=wv&3) -----------------
    const int wv   = tid >> 6;        // 0..7
    const int lane = tid & 63;
    const int mrow = lane & 15;
    const int kq   = lane >> 4;
    const int mh   = wv >> 2;         // M-half: rows [mh*64, mh*64+64)
    const int nw   = wv & 3;          // N-quarter

    f32x4 acc[4][2];
#pragma unroll
    for (int mt = 0; mt < 4; ++mt)
#pragma unroll
        for (int ntl = 0; ntl < 2; ++ntl)
            acc[mt][ntl] = (f32x4){0.f, 0.f, 0.f, 0.f};

#pragma unroll
    for (int ntl = 0; ntl < 2; ++ntl) {
        const int n = (nw * 2 + ntl) * 16 + mrow;
        half4_t Bh[8];
#pragma unroll
        for (int ks = 0; ks < 8; ++ks)
            Bh[ks] = *(const half4_t*)(w2t_hi + n * D_ + ks * 16 + kq * 4);
#pragma unroll
        for (int mt = 0; mt < 4; ++mt) {
            const int row = mh * 64 + mt * 16 + mrow;
#pragma unroll
            for (int ks = 0; ks < 8; ++ks) {
                const half4_t Ah = *(const half4_t*)&smem_h[row][ks * 16 + kq * 4];
                acc[mt][ntl] = __builtin_amdgcn_mfma_f32_16x16x16f16(
                    Ah, Bh[ks], acc[mt][ntl], 0, 0, 0);
            }
        }
    }
    __syncthreads();   // all h reads done -> safe to alias kappa

    // D write (f16): row = (lane>>4)*4+reg, col = lane&15 (m89-verified)
#pragma unroll
    for (int mt = 0; mt < 4; ++mt)
#pragma unroll
        for (int ntl = 0; ntl < 2; ++ntl) {
            const int col = (nw * 2 + ntl) * 16 + mrow;
#pragma unroll
            for (int r = 0; r < 4; ++r)
                kappa[mh * 64 + mt * 16 + kq * 4 + r][col] = (_Float16)acc[mt][ntl][r];
        }
    __syncthreads();

    // ---- Epilogue: gather feats, weighted reduce, LayerNorm -------------
    const int gq = qb16 + qs;
    const int bb = gq >> 15;
    const float4 b2v = *(const float4*)(b2 + dg * 4);

    float o0 = 0.0f, o1 = 0.0f, o2 = 0.0f, o3 = 0.0f;
#pragma unroll
    for (int k = 0; k < 8; ++k) {
        const half4_t kp = *(const half4_t*)&kappa[qs * 8 + k][dg * 4];
        const float4 f =
            *(const float4*)(feats + ((size_t)bb * N_ + sid[qs][k]) * D_ + dg * 4);
        const float wk = swt[qs][k];
        o0 += wk * f.x * ((float)kp[0] + b2v.x);
        o1 += wk * f.y * ((float)kp[1] + b2v.y);
        o2 += wk * f.z * ((float)kp[2] + b2v.z);
        o3 += wk * f.w * ((float)kp[3] + b2v.w);
    }

    float s = o0 + o1 + o2 + o3;
#pragma unroll
    for (int off = 16; off > 0; off >>= 1) s += __shfl_xor(s, off, 32);
    const float mu = s * (1.0f / 128.0f);
    const float v0 = o0 - mu, v1 = o1 - mu, v2 = o2 - mu, v3 = o3 - mu;
    float vs = v0 * v0 + v1 * v1 + v2 * v2 + v3 * v3;
#pragma unroll
    for (int off = 16; off > 0; off >>= 1) vs += __shfl_xor(vs, off, 32);
    const float inv = 1.0f / sqrtf(vs * (1.0f / 128.0f) + 1e-5f);

    const float4 gv = *(const float4*)(gmm + dg * 4);
    const float4 bv = *(const float4*)(bta + dg * 4);
    float4 ov;
    ov.x = v0 * inv * gv.x + bv.x;
    ov.y = v1 * inv * gv.y + bv.y;
    ov.z = v2 * inv * gv.z + bv.z;
    ov.w = v3 * inv * gv.w + bv.w;
    *(float4*)(out + (size_t)gq * D_ + dg * 4) = ov;
}

// ---------------------------------------------------------------------------
extern "C" void kernel_launch(void* const* d_in, const int* in_sizes, int n_in,
                              void* d_out, int out_size, void* d_ws, size_t ws_size,
                              hipStream_t stream)
{
    (void)in_sizes; (void)n_in; (void)out_size; (void)ws_size;
    const float* grid_c = (const float*)d_in[0];
    const float* pts    = (const float*)d_in[1];
    const float* feats  = (const float*)d_in[2];
    const float* W1     = (const float*)d_in[3];
    const float* b1     = (const float*)d_in[4];
    const float* W2     = (const float*)d_in[5];
    const float* b2     = (const float*)d_in[6];
    const float* gmm    = (const float*)d_in[7];
    const float* bta    = (const float*)d_in[8];
    float* out = (float*)d_out;

    char* w = (char*)d_ws;
    int*    kidx   = (int*)(w);                  // 2 MB
    float*  kw     = (float*)(w + 2097152);      // -> 4194304
    float4* p4s    = (float4*)(w + 4194304);     // -> 4325376
    float4* q4s    = (float4*)(w + 4325376);     // -> 5373952
    int*    sidx   = (int*)(w + 5373952);        // -> 5406720
    int*    qmap   = (int*)(w + 5406720);        // -> 5668864
    int*    cstart = (int*)(w + 5668864);        // [2][NC+1] -> 5701640
    int*    qstart = (int*)(w + 5701640);        // [2][NC+1] -> 5734416
    int*    ccur   = (int*)(w + 5734416);        // [2][NC]   -> 5767184
    int*    qcur   = (int*)(w + 5767184);        // [2][NC]   -> 5799952
    int*    hist   = (int*)(w + 5799952);        // [2][NC]   -> 5832720
    int*    qhist  = (int*)(w + 5832720);        // [2][NC]   -> 5865488
    _Float16* w2t_hi = (_Float16*)(w + 5865488); // 32 KB -> 5898256
    (void)qhist; (void)qcur;

    hipMemsetAsync(hist, 0, (size_t)2 * B_ * NC_ * sizeof(int), stream);
    prep_hist_all<<<(B_ * (N_ + M_) + 255) / 256, 256, 0, stream>>>(
        pts, grid_c, hist);
    prep_scan<<<2 * B_, 256, 0, stream>>>(hist, cstart, ccur);
    prep_scatter_all<<<(B_ * (N_ + M_) + D_ * D_ + 255) / 256, 256, 0, stream>>>(
        pts, grid_c, W2, ccur, p4s, sidx, q4s, qmap, w2t_hi);
    knn_kernel<<<(B_ * NC_) / 4, 256, 0, stream>>>(q4s, qmap, p4s, sidx, cstart,
                                                   qstart, kidx, kw);
    gno_kernel<<<(B_ * M_) / 16, 512, 0, stream>>>(grid_c, pts, feats, W1, b1,
                                                   w2t_hi, b2, gmm, bta,
                                                   kidx, kw, out);
}